// Round 2
// baseline (221.345 us; speedup 1.0000x reference)
//
#include <hip/hip_runtime.h>

#define N_ 1024
#define S_ 8
#define I_ 128
#define F_ 1024
#define M_ 512

typedef unsigned short ushort_t;
typedef __attribute__((ext_vector_type(8))) short bf16x8;
typedef __attribute__((ext_vector_type(4))) float f32x4;

__device__ __forceinline__ unsigned short f2bf(float x) {
    unsigned int u = __float_as_uint(x);
    u += 0x7fffu + ((u >> 16) & 1u);   // round-to-nearest-even
    return (unsigned short)(u >> 16);
}

__device__ __forceinline__ float sigmoidf_(float x) {
    return 1.f / (1.f + __expf(-x));
}
__device__ __forceinline__ float tanhf_(float x) {
    float xc = fminf(fmaxf(x, -15.f), 15.f);
    float e = __expf(2.f * xc);
    return (e - 1.f) / (e + 1.f);
}

__device__ __forceinline__ void gload_lds16(const ushort_t* g, ushort_t* l) {
    __builtin_amdgcn_global_load_lds((const __attribute__((address_space(1))) void*)g,
                                     (__attribute__((address_space(3))) void*)l, 16, 0, 0);
}

// ---- fp32 -> bf16 conversion of modulation, Wxi, Wxg, Wxo, Wout into ws ----
// ws layout (bf16 elems): xb@0 (1M), wib@1M, wgb@2M, wob@3M, woutb@4M (4M), hb@8M (8M)
__global__ __launch_bounds__(256) void k_convert(
    const float* __restrict__ mod, const float* __restrict__ wxi,
    const float* __restrict__ wxg, const float* __restrict__ wxo,
    const float* __restrict__ wout, ushort_t* __restrict__ ws) {
    unsigned v = blockIdx.x * 256u + threadIdx.x;  // float4 index, 0..2097151
    const float4* src; unsigned idx; ushort_t* dst;
    if (v < 262144u)       { src = (const float4*)mod;  idx = v;            dst = ws; }
    else if (v < 524288u)  { src = (const float4*)wxi;  idx = v - 262144u;  dst = ws + 1048576; }
    else if (v < 786432u)  { src = (const float4*)wxg;  idx = v - 524288u;  dst = ws + 2097152; }
    else if (v < 1048576u) { src = (const float4*)wxo;  idx = v - 786432u;  dst = ws + 3145728; }
    else                   { src = (const float4*)wout; idx = v - 1048576u; dst = ws + 4194304; }
    float4 f = src[idx];
    ushort4 o;
    o.x = f2bf(f.x); o.y = f2bf(f.y); o.z = f2bf(f.z); o.w = f2bf(f.w);
    ((ushort4*)dst)[idx] = o;
}

// ---- fused 3-gate GEMM + LSTM elementwise -> h (bf16) ----
// Block tile: 128 (n) x 64 (f), BK=64, padded LDS stride 72 elems (bank rotate 4/row).
// 4 waves as 2x2 (wave tile 64x32). LDS 45 KB -> 2 blocks/CU.
__global__ __launch_bounds__(256, 2) void k_gates(
    const ushort_t* __restrict__ xb, const ushort_t* __restrict__ wib,
    const ushort_t* __restrict__ wgb, const ushort_t* __restrict__ wob,
    const float* __restrict__ bi, const float* __restrict__ bg,
    const float* __restrict__ bo, ushort_t* __restrict__ hb) {
    const int s  = blockIdx.z;
    const int n0 = blockIdx.y * 128;
    const int f0 = blockIdx.x * 64;
    // padded: 9 chunks (of 8 elems) per row; chunk 8 is pad (written, never read)
    __shared__ ushort_t sA[128 * 72];
    __shared__ ushort_t sB[3][64 * 72];
    const int tid  = threadIdx.x;
    const int lane = tid & 63;
    const int cl   = lane & 15;
    const int quad = lane >> 4;
    const int w    = tid >> 6;
    const int wm   = (w >> 1) * 64;  // wave row offset (n)
    const int wn   = (w & 1) * 32;   // wave col offset (f)

    f32x4 acc[3][4][2];
    #pragma unroll
    for (int g = 0; g < 3; ++g)
        #pragma unroll
        for (int mt = 0; mt < 4; ++mt)
            #pragma unroll
            for (int nt = 0; nt < 2; ++nt)
                acc[g][mt][nt] = (f32x4){0.f, 0.f, 0.f, 0.f};

    const ushort_t* wb0 = wib + (size_t)s * (F_ * I_);
    const ushort_t* wb1 = wgb + (size_t)s * (F_ * I_);
    const ushort_t* wb2 = wob + (size_t)s * (F_ * I_);

    for (int k0 = 0; k0 < 128; k0 += 64) {
        // stage A: 128 rows x 9 chunks = 1152 chunks (wave-uniform guard: 1152%64==0)
        #pragma unroll
        for (int i = 0; i < 5; ++i) {
            unsigned c = (unsigned)tid + i * 256u;
            if (c < 1152u) {
                unsigned row = c / 9u, kc = c % 9u;
                unsigned kce = kc < 8u ? kc : 7u;
                gload_lds16(xb + (size_t)(n0 + row) * (S_ * I_) + s * I_ + k0 + kce * 8,
                            sA + c * 8);
            }
        }
        // stage B (3 gates): 64 x 9 = 576 chunks each (576%64==0 -> wave-uniform)
        #pragma unroll
        for (int i = 0; i < 3; ++i) {
            unsigned c = (unsigned)tid + i * 256u;
            if (c < 576u) {
                unsigned row = c / 9u, kc = c % 9u;
                unsigned kce = kc < 8u ? kc : 7u;
                size_t goff = (size_t)(f0 + row) * I_ + k0 + kce * 8;
                gload_lds16(wb0 + goff, &sB[0][c * 8]);
                gload_lds16(wb1 + goff, &sB[1][c * 8]);
                gload_lds16(wb2 + goff, &sB[2][c * 8]);
            }
        }
        __syncthreads();
        #pragma unroll
        for (int kk = 0; kk < 2; ++kk) {
            const int kb = kk * 32 + quad * 8;
            bf16x8 a[4];
            #pragma unroll
            for (int mt = 0; mt < 4; ++mt)
                a[mt] = *(const bf16x8*)(sA + (wm + mt * 16 + cl) * 72 + kb);
            #pragma unroll
            for (int g = 0; g < 3; ++g) {
                #pragma unroll
                for (int nt = 0; nt < 2; ++nt) {
                    bf16x8 b = *(const bf16x8*)(&sB[g][(wn + nt * 16 + cl) * 72 + kb]);
                    #pragma unroll
                    for (int mt = 0; mt < 4; ++mt)
                        acc[g][mt][nt] = __builtin_amdgcn_mfma_f32_16x16x32_bf16(
                            a[mt], b, acc[g][mt][nt], 0, 0, 0);
                }
            }
        }
        __syncthreads();
    }

    // epilogue: i=sig, g=tanh, o=sig; c=i*g; h=o*tanh(c)
    #pragma unroll
    for (int nt = 0; nt < 2; ++nt) {
        int fc = f0 + wn + nt * 16 + cl;
        float bii = bi[s * F_ + fc], bgg = bg[s * F_ + fc], boo = bo[s * F_ + fc];
        #pragma unroll
        for (int mt = 0; mt < 4; ++mt) {
            #pragma unroll
            for (int r = 0; r < 4; ++r) {
                int nr = n0 + wm + mt * 16 + quad * 4 + r;
                float pi = acc[0][mt][nt][r] + bii;
                float pg = acc[1][mt][nt][r] + bgg;
                float po = acc[2][mt][nt][r] + boo;
                float hv = sigmoidf_(po) * tanhf_(sigmoidf_(pi) * tanhf_(pg));
                hb[(size_t)s * (N_ * F_) + (size_t)nr * F_ + fc] = f2bf(hv);
            }
        }
    }
}

// ---- out GEMM: out[n, s*M+m] = sum_f h[s,n,f]*Wout[s,m,f] + bout[s,m] ----
// Block tile: 128 (n) x 64 (m), BK=128, padded LDS stride 136 elems.
// 4 waves as 2x2 (wave tile 64x32). LDS 51 KB -> 2 blocks/CU; grid 512 = 2/CU.
__global__ __launch_bounds__(256, 2) void k_out(
    const ushort_t* __restrict__ hb, const ushort_t* __restrict__ woutb,
    const float* __restrict__ bout, float* __restrict__ out) {
    const int s  = blockIdx.z;
    const int n0 = blockIdx.y * 128;
    const int m0 = blockIdx.x * 64;
    // padded: 17 chunks per row; chunk 16 is pad
    __shared__ ushort_t sA[128 * 136];
    __shared__ ushort_t sB[64 * 136];
    const int tid  = threadIdx.x;
    const int lane = tid & 63;
    const int cl   = lane & 15;
    const int quad = lane >> 4;
    const int w    = tid >> 6;
    const int wm   = (w >> 1) * 64;
    const int wn   = (w & 1) * 32;

    f32x4 acc[4][2];
    #pragma unroll
    for (int mt = 0; mt < 4; ++mt)
        #pragma unroll
        for (int nt = 0; nt < 2; ++nt)
            acc[mt][nt] = (f32x4){0.f, 0.f, 0.f, 0.f};

    const ushort_t* ha = hb + (size_t)s * (N_ * F_);
    const ushort_t* wa = woutb + (size_t)s * (M_ * F_);

    for (int k0 = 0; k0 < 1024; k0 += 128) {
        // stage A: 128 x 17 = 2176 chunks (2176%64==0 -> wave-uniform guard)
        #pragma unroll
        for (int i = 0; i < 9; ++i) {
            unsigned c = (unsigned)tid + i * 256u;
            if (c < 2176u) {
                unsigned row = c / 17u, kc = c % 17u;
                unsigned kce = kc < 16u ? kc : 15u;
                gload_lds16(ha + (size_t)(n0 + row) * F_ + k0 + kce * 8, sA + c * 8);
            }
        }
        // stage B: 64 x 17 = 1088 chunks (1088%64==0)
        #pragma unroll
        for (int i = 0; i < 5; ++i) {
            unsigned c = (unsigned)tid + i * 256u;
            if (c < 1088u) {
                unsigned row = c / 17u, kc = c % 17u;
                unsigned kce = kc < 16u ? kc : 15u;
                gload_lds16(wa + (size_t)(m0 + row) * F_ + k0 + kce * 8, sB + c * 8);
            }
        }
        __syncthreads();
        #pragma unroll
        for (int kk = 0; kk < 4; ++kk) {
            const int kb = kk * 32 + quad * 8;
            bf16x8 a[4], b[2];
            #pragma unroll
            for (int mt = 0; mt < 4; ++mt)
                a[mt] = *(const bf16x8*)(sA + (wm + mt * 16 + cl) * 136 + kb);
            #pragma unroll
            for (int nt = 0; nt < 2; ++nt)
                b[nt] = *(const bf16x8*)(sB + (wn + nt * 16 + cl) * 136 + kb);
            #pragma unroll
            for (int nt = 0; nt < 2; ++nt)
                #pragma unroll
                for (int mt = 0; mt < 4; ++mt)
                    acc[mt][nt] = __builtin_amdgcn_mfma_f32_16x16x32_bf16(
                        a[mt], b[nt], acc[mt][nt], 0, 0, 0);
        }
        __syncthreads();
    }

    #pragma unroll
    for (int nt = 0; nt < 2; ++nt) {
        int mc = m0 + wn + nt * 16 + cl;
        float bb = bout[s * M_ + mc];
        #pragma unroll
        for (int mt = 0; mt < 4; ++mt) {
            #pragma unroll
            for (int r = 0; r < 4; ++r) {
                int nr = n0 + wm + mt * 16 + quad * 4 + r;
                out[(size_t)nr * (S_ * M_) + s * M_ + mc] = acc[mt][nt][r] + bb;
            }
        }
    }
}

extern "C" void kernel_launch(void* const* d_in, const int* in_sizes, int n_in,
                              void* d_out, int out_size, void* d_ws, size_t ws_size,
                              hipStream_t stream) {
    const float* mod  = (const float*)d_in[0];
    const float* Wxi  = (const float*)d_in[1];
    const float* bi   = (const float*)d_in[3];
    const float* Wxg  = (const float*)d_in[7];
    const float* bg   = (const float*)d_in[9];
    const float* Wxo  = (const float*)d_in[10];
    const float* bo   = (const float*)d_in[12];
    const float* Wout = (const float*)d_in[13];
    const float* bout = (const float*)d_in[14];

    ushort_t* ws  = (ushort_t*)d_ws;
    ushort_t* xb  = ws;
    ushort_t* wib = ws + 1048576;
    ushort_t* wgb = ws + 2097152;
    ushort_t* wob = ws + 3145728;
    ushort_t* wtb = ws + 4194304;
    ushort_t* hb  = ws + 8388608;

    k_convert<<<8192, 256, 0, stream>>>(mod, Wxi, Wxg, Wxo, Wout, ws);
    k_gates<<<dim3(16, 8, 8), 256, 0, stream>>>(xb, wib, wgb, wob, bi, bg, bo, hb);
    k_out<<<dim3(8, 8, 8), 256, 0, stream>>>(hb, wtb, bout, (float*)d_out);
}

// Round 3
// 216.550 us; speedup vs baseline: 1.0221x; 1.0221x over previous
//
#include <hip/hip_runtime.h>

#define N_ 1024
#define S_ 8
#define I_ 128
#define F_ 1024
#define M_ 512

typedef unsigned short ushort_t;
typedef __attribute__((ext_vector_type(8))) short bf16x8;
typedef __attribute__((ext_vector_type(4))) float f32x4;

__device__ __forceinline__ unsigned short f2bf(float x) {
    unsigned int u = __float_as_uint(x);
    u += 0x7fffu + ((u >> 16) & 1u);   // round-to-nearest-even
    return (unsigned short)(u >> 16);
}

__device__ __forceinline__ float sigmoidf_(float x) {
    return 1.f / (1.f + __expf(-x));
}
__device__ __forceinline__ float tanhf_(float x) {
    float xc = fminf(fmaxf(x, -15.f), 15.f);
    float e = __expf(2.f * xc);
    return (e - 1.f) / (e + 1.f);
}

__device__ __forceinline__ void gload_lds16(const ushort_t* g, ushort_t* l) {
    __builtin_amdgcn_global_load_lds((const __attribute__((address_space(1))) void*)g,
                                     (__attribute__((address_space(3))) void*)l, 16, 0, 0);
}

// ---- fp32 -> bf16 conversion of modulation, Wxi, Wxg, Wxo, Wout into ws ----
// ws layout (bf16 elems): xb@0 (1M), wib@1M, wgb@2M, wob@3M, woutb@4M (4M), hb@8M (8M)
__global__ __launch_bounds__(256) void k_convert(
    const float* __restrict__ mod, const float* __restrict__ wxi,
    const float* __restrict__ wxg, const float* __restrict__ wxo,
    const float* __restrict__ wout, ushort_t* __restrict__ ws) {
    unsigned v = blockIdx.x * 256u + threadIdx.x;  // float4 index, 0..2097151
    const float4* src; unsigned idx; ushort_t* dst;
    if (v < 262144u)       { src = (const float4*)mod;  idx = v;            dst = ws; }
    else if (v < 524288u)  { src = (const float4*)wxi;  idx = v - 262144u;  dst = ws + 1048576; }
    else if (v < 786432u)  { src = (const float4*)wxg;  idx = v - 524288u;  dst = ws + 2097152; }
    else if (v < 1048576u) { src = (const float4*)wxo;  idx = v - 786432u;  dst = ws + 3145728; }
    else                   { src = (const float4*)wout; idx = v - 1048576u; dst = ws + 4194304; }
    float4 f = src[idx];
    ushort4 o;
    o.x = f2bf(f.x); o.y = f2bf(f.y); o.z = f2bf(f.z); o.w = f2bf(f.w);
    ((ushort4*)dst)[idx] = o;
}

// ---- fused 3-gate GEMM + LSTM elementwise -> h (bf16) ----
// Block tile: 128 (n) x 64 (f), BK=64, padded LDS stride 72 elems.
// XCD swizzle: all 16 f-tiles sharing an (n,s) x-tile map to the same XCD
// (same linear%8) so the x-tile is fetched into one L2, not eight.
__global__ __launch_bounds__(256, 2) void k_gates(
    const ushort_t* __restrict__ xb, const ushort_t* __restrict__ wib,
    const ushort_t* __restrict__ wgb, const ushort_t* __restrict__ wob,
    const float* __restrict__ bi, const float* __restrict__ bg,
    const float* __restrict__ bo, ushort_t* __restrict__ hb) {
    const int Lb   = blockIdx.x + 16 * blockIdx.y + 128 * blockIdx.z;
    const int xcd  = Lb & 7;
    const int slot = Lb >> 3;          // 0..127
    const int f0   = (slot & 15) * 64; // 16 f-tiles consecutive within an XCD
    const int s    = slot >> 4;        // 0..7
    const int n0   = (((xcd + s) & 7)) * 128;
    // padded: 9 chunks (of 8 elems) per row; chunk 8 is pad (written, never read)
    __shared__ ushort_t sA[128 * 72];
    __shared__ ushort_t sB[3][64 * 72];
    const int tid  = threadIdx.x;
    const int lane = tid & 63;
    const int cl   = lane & 15;
    const int quad = lane >> 4;
    const int w    = tid >> 6;
    const int wm   = (w >> 1) * 64;  // wave row offset (n)
    const int wn   = (w & 1) * 32;   // wave col offset (f)

    f32x4 acc[3][4][2];
    #pragma unroll
    for (int g = 0; g < 3; ++g)
        #pragma unroll
        for (int mt = 0; mt < 4; ++mt)
            #pragma unroll
            for (int nt = 0; nt < 2; ++nt)
                acc[g][mt][nt] = (f32x4){0.f, 0.f, 0.f, 0.f};

    const ushort_t* wb0 = wib + (size_t)s * (F_ * I_);
    const ushort_t* wb1 = wgb + (size_t)s * (F_ * I_);
    const ushort_t* wb2 = wob + (size_t)s * (F_ * I_);

    for (int k0 = 0; k0 < 128; k0 += 64) {
        // stage A: 128 rows x 9 chunks = 1152 chunks (wave-uniform guard: 1152%64==0)
        #pragma unroll
        for (int i = 0; i < 5; ++i) {
            unsigned c = (unsigned)tid + i * 256u;
            if (c < 1152u) {
                unsigned row = c / 9u, kc = c % 9u;
                unsigned kce = kc < 8u ? kc : 7u;
                gload_lds16(xb + (size_t)(n0 + row) * (S_ * I_) + s * I_ + k0 + kce * 8,
                            sA + c * 8);
            }
        }
        // stage B (3 gates): 64 x 9 = 576 chunks each (576%64==0 -> wave-uniform)
        #pragma unroll
        for (int i = 0; i < 3; ++i) {
            unsigned c = (unsigned)tid + i * 256u;
            if (c < 576u) {
                unsigned row = c / 9u, kc = c % 9u;
                unsigned kce = kc < 8u ? kc : 7u;
                size_t goff = (size_t)(f0 + row) * I_ + k0 + kce * 8;
                gload_lds16(wb0 + goff, &sB[0][c * 8]);
                gload_lds16(wb1 + goff, &sB[1][c * 8]);
                gload_lds16(wb2 + goff, &sB[2][c * 8]);
            }
        }
        __syncthreads();
        #pragma unroll
        for (int kk = 0; kk < 2; ++kk) {
            const int kb = kk * 32 + quad * 8;
            bf16x8 a[4];
            #pragma unroll
            for (int mt = 0; mt < 4; ++mt)
                a[mt] = *(const bf16x8*)(sA + (wm + mt * 16 + cl) * 72 + kb);
            #pragma unroll
            for (int g = 0; g < 3; ++g) {
                #pragma unroll
                for (int nt = 0; nt < 2; ++nt) {
                    bf16x8 b = *(const bf16x8*)(&sB[g][(wn + nt * 16 + cl) * 72 + kb]);
                    #pragma unroll
                    for (int mt = 0; mt < 4; ++mt)
                        acc[g][mt][nt] = __builtin_amdgcn_mfma_f32_16x16x32_bf16(
                            a[mt], b, acc[g][mt][nt], 0, 0, 0);
                }
            }
        }
        __syncthreads();
    }

    // epilogue: i=sig, g=tanh, o=sig; c=i*g; h=o*tanh(c)
    #pragma unroll
    for (int nt = 0; nt < 2; ++nt) {
        int fc = f0 + wn + nt * 16 + cl;
        float bii = bi[s * F_ + fc], bgg = bg[s * F_ + fc], boo = bo[s * F_ + fc];
        #pragma unroll
        for (int mt = 0; mt < 4; ++mt) {
            #pragma unroll
            for (int r = 0; r < 4; ++r) {
                int nr = n0 + wm + mt * 16 + quad * 4 + r;
                float pi = acc[0][mt][nt][r] + bii;
                float pg = acc[1][mt][nt][r] + bgg;
                float po = acc[2][mt][nt][r] + boo;
                float hv = sigmoidf_(po) * tanhf_(sigmoidf_(pi) * tanhf_(pg));
                hb[(size_t)s * (N_ * F_) + (size_t)nr * F_ + fc] = f2bf(hv);
            }
        }
    }
}

// ---- out GEMM: out[n, s*M+m] = sum_f h[s,n,f]*Wout[s,m,f] + bout[s,m] ----
// Block tile: 128 (n) x 64 (m), BK=128, padded LDS stride 136 elems.
// XCD swizzle: all 8 m-tiles sharing an (n,s) h-tile (256 KB) map to the same
// XCD so h is fetched into one L2 instead of eight (~131 MB -> ~16 MB).
__global__ __launch_bounds__(256, 2) void k_out(
    const ushort_t* __restrict__ hb, const ushort_t* __restrict__ woutb,
    const float* __restrict__ bout, float* __restrict__ out) {
    const int Lb   = blockIdx.x + 8 * blockIdx.y + 64 * blockIdx.z;
    const int xcd  = Lb & 7;
    const int slot = Lb >> 3;         // 0..63
    const int m0   = (slot & 7) * 64; // 8 m-tiles consecutive within an XCD
    const int s    = slot >> 3;       // 0..7
    const int n0   = (((xcd + s) & 7)) * 128;
    // padded: 17 chunks per row; chunk 16 is pad
    __shared__ ushort_t sA[128 * 136];
    __shared__ ushort_t sB[64 * 136];
    const int tid  = threadIdx.x;
    const int lane = tid & 63;
    const int cl   = lane & 15;
    const int quad = lane >> 4;
    const int w    = tid >> 6;
    const int wm   = (w >> 1) * 64;
    const int wn   = (w & 1) * 32;

    f32x4 acc[4][2];
    #pragma unroll
    for (int mt = 0; mt < 4; ++mt)
        #pragma unroll
        for (int nt = 0; nt < 2; ++nt)
            acc[mt][nt] = (f32x4){0.f, 0.f, 0.f, 0.f};

    const ushort_t* ha = hb + (size_t)s * (N_ * F_);
    const ushort_t* wa = woutb + (size_t)s * (M_ * F_);

    for (int k0 = 0; k0 < 1024; k0 += 128) {
        // stage A: 128 x 17 = 2176 chunks (2176%64==0 -> wave-uniform guard)
        #pragma unroll
        for (int i = 0; i < 9; ++i) {
            unsigned c = (unsigned)tid + i * 256u;
            if (c < 2176u) {
                unsigned row = c / 17u, kc = c % 17u;
                unsigned kce = kc < 16u ? kc : 15u;
                gload_lds16(ha + (size_t)(n0 + row) * F_ + k0 + kce * 8, sA + c * 8);
            }
        }
        // stage B: 64 x 17 = 1088 chunks (1088%64==0)
        #pragma unroll
        for (int i = 0; i < 5; ++i) {
            unsigned c = (unsigned)tid + i * 256u;
            if (c < 1088u) {
                unsigned row = c / 17u, kc = c % 17u;
                unsigned kce = kc < 16u ? kc : 15u;
                gload_lds16(wa + (size_t)(m0 + row) * F_ + k0 + kce * 8, sB + c * 8);
            }
        }
        __syncthreads();
        #pragma unroll
        for (int kk = 0; kk < 4; ++kk) {
            const int kb = kk * 32 + quad * 8;
            bf16x8 a[4], b[2];
            #pragma unroll
            for (int mt = 0; mt < 4; ++mt)
                a[mt] = *(const bf16x8*)(sA + (wm + mt * 16 + cl) * 136 + kb);
            #pragma unroll
            for (int nt = 0; nt < 2; ++nt)
                b[nt] = *(const bf16x8*)(sB + (wn + nt * 16 + cl) * 136 + kb);
            #pragma unroll
            for (int nt = 0; nt < 2; ++nt)
                #pragma unroll
                for (int mt = 0; mt < 4; ++mt)
                    acc[mt][nt] = __builtin_amdgcn_mfma_f32_16x16x32_bf16(
                        a[mt], b[nt], acc[mt][nt], 0, 0, 0);
        }
        __syncthreads();
    }

    #pragma unroll
    for (int nt = 0; nt < 2; ++nt) {
        int mc = m0 + wn + nt * 16 + cl;
        float bb = bout[s * M_ + mc];
        #pragma unroll
        for (int mt = 0; mt < 4; ++mt) {
            #pragma unroll
            for (int r = 0; r < 4; ++r) {
                int nr = n0 + wm + mt * 16 + quad * 4 + r;
                out[(size_t)nr * (S_ * M_) + s * M_ + mc] = acc[mt][nt][r] + bb;
            }
        }
    }
}

extern "C" void kernel_launch(void* const* d_in, const int* in_sizes, int n_in,
                              void* d_out, int out_size, void* d_ws, size_t ws_size,
                              hipStream_t stream) {
    const float* mod  = (const float*)d_in[0];
    const float* Wxi  = (const float*)d_in[1];
    const float* bi   = (const float*)d_in[3];
    const float* Wxg  = (const float*)d_in[7];
    const float* bg   = (const float*)d_in[9];
    const float* Wxo  = (const float*)d_in[10];
    const float* bo   = (const float*)d_in[12];
    const float* Wout = (const float*)d_in[13];
    const float* bout = (const float*)d_in[14];

    ushort_t* ws  = (ushort_t*)d_ws;
    ushort_t* xb  = ws;
    ushort_t* wib = ws + 1048576;
    ushort_t* wgb = ws + 2097152;
    ushort_t* wob = ws + 3145728;
    ushort_t* wtb = ws + 4194304;
    ushort_t* hb  = ws + 8388608;

    k_convert<<<8192, 256, 0, stream>>>(mod, Wxi, Wxg, Wxo, Wout, ws);
    k_gates<<<dim3(16, 8, 8), 256, 0, stream>>>(xb, wib, wgb, wob, bi, bg, bo, hb);
    k_out<<<dim3(8, 8, 8), 256, 0, stream>>>(hb, wtb, bout, (float*)d_out);
}

// Round 4
// 211.776 us; speedup vs baseline: 1.0452x; 1.0225x over previous
//
#include <hip/hip_runtime.h>

#define N_ 1024
#define S_ 8
#define I_ 128
#define F_ 1024
#define M_ 512

typedef unsigned short ushort_t;
typedef __attribute__((ext_vector_type(8))) short bf16x8;
typedef __attribute__((ext_vector_type(4))) float f32x4;

__device__ __forceinline__ unsigned short f2bf(float x) {
    unsigned int u = __float_as_uint(x);
    u += 0x7fffu + ((u >> 16) & 1u);   // round-to-nearest-even
    return (unsigned short)(u >> 16);
}

__device__ __forceinline__ float sigmoidf_(float x) {
    return 1.f / (1.f + __expf(-x));
}
__device__ __forceinline__ float tanhf_(float x) {
    float xc = fminf(fmaxf(x, -15.f), 15.f);
    float e = __expf(2.f * xc);
    return (e - 1.f) / (e + 1.f);
}

__device__ __forceinline__ void gload_lds16(const ushort_t* g, ushort_t* l) {
    __builtin_amdgcn_global_load_lds((const __attribute__((address_space(1))) void*)g,
                                     (__attribute__((address_space(3))) void*)l, 16, 0, 0);
}

// ---- fp32 -> bf16 conversion of modulation, Wxi, Wxg, Wxo, Wout into ws ----
// ws layout (bf16 elems): xb@0 (1M), wib@1M, wgb@2M, wob@3M, woutb@4M (4M), hb@8M (8M)
__global__ __launch_bounds__(256) void k_convert(
    const float* __restrict__ mod, const float* __restrict__ wxi,
    const float* __restrict__ wxg, const float* __restrict__ wxo,
    const float* __restrict__ wout, ushort_t* __restrict__ ws) {
    unsigned v = blockIdx.x * 256u + threadIdx.x;  // float4 index, 0..2097151
    const float4* src; unsigned idx; ushort_t* dst;
    if (v < 262144u)       { src = (const float4*)mod;  idx = v;            dst = ws; }
    else if (v < 524288u)  { src = (const float4*)wxi;  idx = v - 262144u;  dst = ws + 1048576; }
    else if (v < 786432u)  { src = (const float4*)wxg;  idx = v - 524288u;  dst = ws + 2097152; }
    else if (v < 1048576u) { src = (const float4*)wxo;  idx = v - 786432u;  dst = ws + 3145728; }
    else                   { src = (const float4*)wout; idx = v - 1048576u; dst = ws + 4194304; }
    float4 f = src[idx];
    ushort4 o;
    o.x = f2bf(f.x); o.y = f2bf(f.y); o.z = f2bf(f.z); o.w = f2bf(f.w);
    ((ushort4*)dst)[idx] = o;
}

// ---- fused 3-gate GEMM + LSTM elementwise -> h (bf16) ----
// Block tile: 128 (n) x 64 (f), BK=64, padded LDS stride 72 elems.
// s-major XCD grouping: xcd = Lb&7 = s. All 128 blocks of stream s land on one
// XCD; its entire working set (x[s] 256 KB + 3 weight slices 768 KB ~= 1 MB)
// fits the 4 MB XCD L2, so every byte crosses the L3/L2 boundary once.
__global__ __launch_bounds__(256, 2) void k_gates(
    const ushort_t* __restrict__ xb, const ushort_t* __restrict__ wib,
    const ushort_t* __restrict__ wgb, const ushort_t* __restrict__ wob,
    const float* __restrict__ bi, const float* __restrict__ bg,
    const float* __restrict__ bo, ushort_t* __restrict__ hb) {
    const int Lb   = blockIdx.x + 16 * blockIdx.y + 128 * blockIdx.z;
    const int s    = Lb & 7;             // stream == XCD
    const int slot = Lb >> 3;            // 0..127
    const int n0   = (slot & 7) * 128;
    const int f0   = (slot >> 3) * 64;
    // padded: 9 chunks (of 8 elems) per row; chunk 8 is pad (written, never read)
    __shared__ ushort_t sA[128 * 72];
    __shared__ ushort_t sB[3][64 * 72];
    const int tid  = threadIdx.x;
    const int lane = tid & 63;
    const int cl   = lane & 15;
    const int quad = lane >> 4;
    const int w    = tid >> 6;
    const int wm   = (w >> 1) * 64;  // wave row offset (n)
    const int wn   = (w & 1) * 32;   // wave col offset (f)

    f32x4 acc[3][4][2];
    #pragma unroll
    for (int g = 0; g < 3; ++g)
        #pragma unroll
        for (int mt = 0; mt < 4; ++mt)
            #pragma unroll
            for (int nt = 0; nt < 2; ++nt)
                acc[g][mt][nt] = (f32x4){0.f, 0.f, 0.f, 0.f};

    const ushort_t* wb0 = wib + (size_t)s * (F_ * I_);
    const ushort_t* wb1 = wgb + (size_t)s * (F_ * I_);
    const ushort_t* wb2 = wob + (size_t)s * (F_ * I_);

    for (int k0 = 0; k0 < 128; k0 += 64) {
        // stage A: 128 rows x 9 chunks = 1152 chunks (wave-uniform guard: 1152%64==0)
        #pragma unroll
        for (int i = 0; i < 5; ++i) {
            unsigned c = (unsigned)tid + i * 256u;
            if (c < 1152u) {
                unsigned row = c / 9u, kc = c % 9u;
                unsigned kce = kc < 8u ? kc : 7u;
                gload_lds16(xb + (size_t)(n0 + row) * (S_ * I_) + s * I_ + k0 + kce * 8,
                            sA + c * 8);
            }
        }
        // stage B (3 gates): 64 x 9 = 576 chunks each (576%64==0 -> wave-uniform)
        #pragma unroll
        for (int i = 0; i < 3; ++i) {
            unsigned c = (unsigned)tid + i * 256u;
            if (c < 576u) {
                unsigned row = c / 9u, kc = c % 9u;
                unsigned kce = kc < 8u ? kc : 7u;
                size_t goff = (size_t)(f0 + row) * I_ + k0 + kce * 8;
                gload_lds16(wb0 + goff, &sB[0][c * 8]);
                gload_lds16(wb1 + goff, &sB[1][c * 8]);
                gload_lds16(wb2 + goff, &sB[2][c * 8]);
            }
        }
        __syncthreads();
        #pragma unroll
        for (int kk = 0; kk < 2; ++kk) {
            const int kb = kk * 32 + quad * 8;
            bf16x8 a[4];
            #pragma unroll
            for (int mt = 0; mt < 4; ++mt)
                a[mt] = *(const bf16x8*)(sA + (wm + mt * 16 + cl) * 72 + kb);
            #pragma unroll
            for (int g = 0; g < 3; ++g) {
                #pragma unroll
                for (int nt = 0; nt < 2; ++nt) {
                    bf16x8 b = *(const bf16x8*)(&sB[g][(wn + nt * 16 + cl) * 72 + kb]);
                    #pragma unroll
                    for (int mt = 0; mt < 4; ++mt)
                        acc[g][mt][nt] = __builtin_amdgcn_mfma_f32_16x16x32_bf16(
                            a[mt], b, acc[g][mt][nt], 0, 0, 0);
                }
            }
        }
        __syncthreads();
    }

    // epilogue: i=sig, g=tanh, o=sig; c=i*g; h=o*tanh(c)
    #pragma unroll
    for (int nt = 0; nt < 2; ++nt) {
        int fc = f0 + wn + nt * 16 + cl;
        float bii = bi[s * F_ + fc], bgg = bg[s * F_ + fc], boo = bo[s * F_ + fc];
        #pragma unroll
        for (int mt = 0; mt < 4; ++mt) {
            #pragma unroll
            for (int r = 0; r < 4; ++r) {
                int nr = n0 + wm + mt * 16 + quad * 4 + r;
                float pi = acc[0][mt][nt][r] + bii;
                float pg = acc[1][mt][nt][r] + bgg;
                float po = acc[2][mt][nt][r] + boo;
                float hv = sigmoidf_(po) * tanhf_(sigmoidf_(pi) * tanhf_(pg));
                hb[(size_t)s * (N_ * F_) + (size_t)nr * F_ + fc] = f2bf(hv);
            }
        }
    }
}

// ---- out GEMM: out[n, s*M+m] = sum_f h[s,n,f]*Wout[s,m,f] + bout[s,m] ----
// Block tile: 128 (n) x 64 (m), BK=128, padded LDS stride 136 elems.
// s-major XCD grouping: xcd = Lb&7 = s. All 64 blocks of stream s on one XCD;
// working set h[s] (2 MB) + Wout[s] (1 MB) fits the 4 MB L2 -> both h and
// weights cross L3/L2 once (was: weights duplicated across 8 XCDs).
__global__ __launch_bounds__(256, 2) void k_out(
    const ushort_t* __restrict__ hb, const ushort_t* __restrict__ woutb,
    const float* __restrict__ bout, float* __restrict__ out) {
    const int Lb   = blockIdx.x + 8 * blockIdx.y + 64 * blockIdx.z;
    const int s    = Lb & 7;            // stream == XCD
    const int slot = Lb >> 3;           // 0..63
    const int n0   = (slot & 7) * 128;
    const int m0   = (slot >> 3) * 64;
    // padded: 17 chunks per row; chunk 16 is pad
    __shared__ ushort_t sA[128 * 136];
    __shared__ ushort_t sB[64 * 136];
    const int tid  = threadIdx.x;
    const int lane = tid & 63;
    const int cl   = lane & 15;
    const int quad = lane >> 4;
    const int w    = tid >> 6;
    const int wm   = (w >> 1) * 64;
    const int wn   = (w & 1) * 32;

    f32x4 acc[4][2];
    #pragma unroll
    for (int mt = 0; mt < 4; ++mt)
        #pragma unroll
        for (int nt = 0; nt < 2; ++nt)
            acc[mt][nt] = (f32x4){0.f, 0.f, 0.f, 0.f};

    const ushort_t* ha = hb + (size_t)s * (N_ * F_);
    const ushort_t* wa = woutb + (size_t)s * (M_ * F_);

    for (int k0 = 0; k0 < 1024; k0 += 128) {
        // stage A: 128 x 17 = 2176 chunks (2176%64==0 -> wave-uniform guard)
        #pragma unroll
        for (int i = 0; i < 9; ++i) {
            unsigned c = (unsigned)tid + i * 256u;
            if (c < 2176u) {
                unsigned row = c / 17u, kc = c % 17u;
                unsigned kce = kc < 16u ? kc : 15u;
                gload_lds16(ha + (size_t)(n0 + row) * F_ + k0 + kce * 8, sA + c * 8);
            }
        }
        // stage B: 64 x 17 = 1088 chunks (1088%64==0)
        #pragma unroll
        for (int i = 0; i < 5; ++i) {
            unsigned c = (unsigned)tid + i * 256u;
            if (c < 1088u) {
                unsigned row = c / 17u, kc = c % 17u;
                unsigned kce = kc < 16u ? kc : 15u;
                gload_lds16(wa + (size_t)(m0 + row) * F_ + k0 + kce * 8, sB + c * 8);
            }
        }
        __syncthreads();
        #pragma unroll
        for (int kk = 0; kk < 4; ++kk) {
            const int kb = kk * 32 + quad * 8;
            bf16x8 a[4], b[2];
            #pragma unroll
            for (int mt = 0; mt < 4; ++mt)
                a[mt] = *(const bf16x8*)(sA + (wm + mt * 16 + cl) * 136 + kb);
            #pragma unroll
            for (int nt = 0; nt < 2; ++nt)
                b[nt] = *(const bf16x8*)(sB + (wn + nt * 16 + cl) * 136 + kb);
            #pragma unroll
            for (int nt = 0; nt < 2; ++nt)
                #pragma unroll
                for (int mt = 0; mt < 4; ++mt)
                    acc[mt][nt] = __builtin_amdgcn_mfma_f32_16x16x32_bf16(
                        a[mt], b[nt], acc[mt][nt], 0, 0, 0);
        }
        __syncthreads();
    }

    #pragma unroll
    for (int nt = 0; nt < 2; ++nt) {
        int mc = m0 + wn + nt * 16 + cl;
        float bb = bout[s * M_ + mc];
        #pragma unroll
        for (int mt = 0; mt < 4; ++mt) {
            #pragma unroll
            for (int r = 0; r < 4; ++r) {
                int nr = n0 + wm + mt * 16 + quad * 4 + r;
                out[(size_t)nr * (S_ * M_) + s * M_ + mc] = acc[mt][nt][r] + bb;
            }
        }
    }
}

extern "C" void kernel_launch(void* const* d_in, const int* in_sizes, int n_in,
                              void* d_out, int out_size, void* d_ws, size_t ws_size,
                              hipStream_t stream) {
    const float* mod  = (const float*)d_in[0];
    const float* Wxi  = (const float*)d_in[1];
    const float* bi   = (const float*)d_in[3];
    const float* Wxg  = (const float*)d_in[7];
    const float* bg   = (const float*)d_in[9];
    const float* Wxo  = (const float*)d_in[10];
    const float* bo   = (const float*)d_in[12];
    const float* Wout = (const float*)d_in[13];
    const float* bout = (const float*)d_in[14];

    ushort_t* ws  = (ushort_t*)d_ws;
    ushort_t* xb  = ws;
    ushort_t* wib = ws + 1048576;
    ushort_t* wgb = ws + 2097152;
    ushort_t* wob = ws + 3145728;
    ushort_t* wtb = ws + 4194304;
    ushort_t* hb  = ws + 8388608;

    k_convert<<<8192, 256, 0, stream>>>(mod, Wxi, Wxg, Wxo, Wout, ws);
    k_gates<<<dim3(16, 8, 8), 256, 0, stream>>>(xb, wib, wgb, wob, bi, bg, bo, hb);
    k_out<<<dim3(8, 8, 8), 256, 0, stream>>>(hb, wtb, bout, (float*)d_out);
}